// Round 3
// 460.919 us; speedup vs baseline: 1.0228x; 1.0228x over previous
//
#include <hip/hip_runtime.h>

// LePEAttention: B=16, H=W=64, C=384, HEADS=12, hd=32, IDX=0 (vertical strips).
// Pipeline: k_prep (cvt x->x16 + lepe) -> k_qkv (MFMA GEMM, strip-permuted store)
//           -> k_attn (block=strip, 4 waves x 3 heads) -> k_proj (+lepe +bias, fp32).
// MFMA layouts (HW-verified): A[m=lane&15][k=quad*8+j]; B mirrored;
//   C/D: col=lane&15, row=quad*4+reg.
// R7: minimal diff from R4 (last known-good run) after two infra failures on R5/R6.
//   ONLY change: k_qkv/k_proj grid is XCD-chunked mt-major (xcd=bid&7 owns a
//   contiguous mt range, nt fastest) so each A-tile's nt-passes hit the same
//   XCD L2. Attacks the 224 MB FETCH (ideal ~51 MB) measured in R4.
//   Epilogues left exactly as R4 (scalar stores) to isolate variables.

typedef _Float16 f16;
typedef _Float16 f16x8 __attribute__((ext_vector_type(8)));
typedef float    f32x4 __attribute__((ext_vector_type(4)));

__device__ __forceinline__ f32x4 mfma_16x16x32(f16x8 a, f16x8 b, f32x4 c) {
  return __builtin_amdgcn_mfma_f32_16x16x32_f16(a, b, c, 0, 0, 0);
}

// async global->LDS 16B copy (dest must be wave-uniform base + lane*16)
__device__ __forceinline__ void gl_lds16(const f16* g, f16* l) {
  __builtin_amdgcn_global_load_lds((const __attribute__((address_space(1))) void*)g,
                                   (__attribute__((address_space(3))) void*)l, 16, 0, 0);
}

// ---------------- fp32 -> fp16 convert (weights) ----------------
__global__ __launch_bounds__(256) void k_cvt(const float* __restrict__ src,
                                             f16* __restrict__ dst, int n8) {
  int i = blockIdx.x * 256 + threadIdx.x;
  if (i >= n8) return;
  const f32x4* s4 = (const f32x4*)src;
  f32x4 a = s4[2 * i], b = s4[2 * i + 1];
  f16x8 o;
#pragma unroll
  for (int j = 0; j < 4; ++j) { o[j] = (f16)a[j]; o[4 + j] = (f16)b[j]; }
  *(f16x8*)&dst[(long)i * 8] = o;
}

// ---------------- fused cvt(x) + LePE conv ----------------
__global__ __launch_bounds__(256) void k_prep(const float* __restrict__ x,
                                              const float* __restrict__ lw,
                                              const float* __restrict__ lb,
                                              f16* __restrict__ x16,
                                              f16* __restrict__ lepe16) {
  __shared__ float ws[9 * 384];
  __shared__ float bs[384];
  for (int i = threadIdx.x; i < 3456; i += 256) {
    int c = i / 9, tap = i - c * 9;
    ws[tap * 384 + (c & 7) * 48 + (c >> 3)] = lw[i];
  }
  for (int i = threadIdx.x; i < 384; i += 256)
    bs[(i & 7) * 48 + (i >> 3)] = lb[i];
  __syncthreads();

  int chunk = blockIdx.x * 256 + threadIdx.x;
  int token = chunk / 48;
  int c0 = (chunk - token * 48) * 8;
  int cg = c0 >> 3;  // 0..47, stride-1 across lanes
  int b = token >> 12, n = token & 4095, h = n >> 6, w = n & 63;
  const float* xb = x + (long)(b << 12) * 384;

  float a8[8];
#pragma unroll
  for (int cc = 0; cc < 8; ++cc) a8[cc] = bs[cc * 48 + cg];
  f16x8 cv;
#pragma unroll
  for (int ky = 0; ky < 3; ++ky) {
    int hh = h + ky - 1;
    if (hh < 0 || hh > 63) continue;
#pragma unroll
    for (int kx = 0; kx < 3; ++kx) {
      int ww = w + kx - 1;
      if (ww < 0 || ww > 63) continue;
      const float* p = xb + (long)((hh << 6) + ww) * 384 + c0;
      float4 u = *(const float4*)p;
      float4 v = *(const float4*)(p + 4);
      float xs[8] = {u.x, u.y, u.z, u.w, v.x, v.y, v.z, v.w};
      if (ky == 1 && kx == 1) {
#pragma unroll
        for (int cc = 0; cc < 8; ++cc) cv[cc] = (f16)xs[cc];
      }
      int tap = ky * 3 + kx;
#pragma unroll
      for (int cc = 0; cc < 8; ++cc)
        a8[cc] += xs[cc] * ws[tap * 384 + cc * 48 + cg];
    }
  }
  f16x8 o;
#pragma unroll
  for (int cc = 0; cc < 8; ++cc) o[cc] = (f16)a8[cc];
  *(f16x8*)&x16[(long)token * 384 + c0] = cv;
  *(f16x8*)&lepe16[(long)token * 384 + c0] = o;
}

// ---------------- QKV GEMM: qkv[perm(t)][1152] = x16 @ w16^T ----------------
// 128x128 tile, BK=64, global_load_lds staging w/ 16B xor swizzle.
// Grid: XCD-chunked, nt fastest within each xcd's contiguous mt range -> each
// A-tile's 9 nt-passes hit the same XCD L2 (A fetched ~once from HBM).
// Store row permutation t=(b,l*64+w) -> prow=(b,w*64+l) for contiguous strips.
__global__ __launch_bounds__(256) void k_qkv(const f16* __restrict__ A,
                                             const f16* __restrict__ Bt,
                                             f16* __restrict__ C) {
  __shared__ alignas(16) f16 As[128 * 64];
  __shared__ alignas(16) f16 Bs[128 * 64];
  const int tid = threadIdx.x;
  const int lane = tid & 63;
  const int wave = tid >> 6;
  const int wr = wave >> 1, wc = wave & 1;
  const int ln = lane & 15, quad = lane >> 4, q8 = quad * 8;
  const int bid = blockIdx.x;
  const int xcd = bid & 7;
  const int s = bid >> 3;        // 0..575
  const int mq = s / 9;          // 0..63
  const int mt = xcd * 64 + mq;  // 0..511
  const int nt = s - mq * 9;     // 0..8
  const long m0 = (long)mt * 128;
  const int n0 = nt * 128;

  f32x4 acc[4][4] = {};
  for (int k0 = 0; k0 < 384; k0 += 64) {
#pragma unroll
    for (int r = 0; r < 4; ++r) {
      int flat = r * 256 + tid;
      int row = flat >> 3, c8 = flat & 7;
      int sc8 = (c8 ^ (row & 7)) * 8;
      gl_lds16(&A[(m0 + row) * 384 + k0 + sc8], &As[flat * 8]);
      gl_lds16(&Bt[(long)(n0 + row) * 384 + k0 + sc8], &Bs[flat * 8]);
    }
    __syncthreads();
#pragma unroll
    for (int ks = 0; ks < 2; ++ks) {
      f16x8 a[4], b[4];
#pragma unroll
      for (int i = 0; i < 4; ++i)
        a[i] = *(const f16x8*)&As[(wr * 64 + i * 16 + ln) * 64 +
                                  ((ks * 4 + quad) ^ (ln & 7)) * 8];
#pragma unroll
      for (int j = 0; j < 4; ++j)
        b[j] = *(const f16x8*)&Bs[(wc * 64 + j * 16 + ln) * 64 +
                                  ((ks * 4 + quad) ^ (ln & 7)) * 8];
#pragma unroll
      for (int i = 0; i < 4; ++i)
#pragma unroll
        for (int j = 0; j < 4; ++j)
          acc[i][j] = mfma_16x16x32(a[i], b[j], acc[i][j]);
    }
    __syncthreads();
  }

#pragma unroll
  for (int i = 0; i < 4; ++i)
#pragma unroll
    for (int j = 0; j < 4; ++j) {
      int gc = n0 + wc * 64 + j * 16 + ln;
#pragma unroll
      for (int r = 0; r < 4; ++r) {
        int t = (int)m0 + wr * 64 + i * 16 + quad * 4 + r;
        int nn = t & 4095;
        long prow = (long)(t & ~4095) + ((nn & 63) << 6) + (nn >> 6);
        C[prow * 1152 + gc] = (f16)acc[i][j][r];
      }
    }
}

// ---------------- attention: block = strip, 4 waves x 3 heads ----------------
// qkv rows are strip-contiguous. Pure store to attnout (lepe added in proj).
__global__ __launch_bounds__(256) void k_attn(const f16* __restrict__ qkv,
                                              f16* __restrict__ attnout) {
  // per-wave LDS (halfs): qs@0 (64x40), ks@2560 (64x40), vt@5120 (32x72).
  // ps (64x72=4608) overlays qs+ks; obuf (64x40) overlays ps. total 7424 h/wave.
  __shared__ alignas(16) f16 shp[4][7424];
  const int lane = threadIdx.x & 63;
  const int wave = threadIdx.x >> 6;
  const int ln = lane & 15, quad = lane >> 4, q8 = quad * 8;
  const int b = blockIdx.x >> 6, w = blockIdx.x & 63;
  const long sbase = (long)b * 4096 + (long)w * 64;  // first permuted row of strip

  f16* qs = shp[wave];
  f16* ks = shp[wave] + 2560;
  f16* vt = shp[wave] + 5120;
  f16* ps = shp[wave];
  f16* obuf = shp[wave];
  const float qscale = 0.17677669529663687f;  // 32^-0.5

  for (int hi = 0; hi < 3; ++hi) {
    const int hh = wave * 3 + hi;
    // load q,k,v (64 tokens x 32 halfs each); rows stride 2304 B, 64 B used
#pragma unroll
    for (int r = 0; r < 4; ++r) {
      int flat = r * 64 + lane;
      int l = flat >> 2, dg = (flat & 3) * 8;
      long ta = (sbase + l) * 1152 + hh * 32 + dg;
      f16x8 qv = *(const f16x8*)&qkv[ta];
      f16x8 kv = *(const f16x8*)&qkv[ta + 384];
      f16x8 vv = *(const f16x8*)&qkv[ta + 768];
      // pre-scale q by 1/sqrt(hd)
#pragma unroll
      for (int ii = 0; ii < 8; ++ii) qv[ii] = (f16)((float)qv[ii] * qscale);
      *(f16x8*)&qs[l * 40 + dg] = qv;
      *(f16x8*)&ks[l * 40 + dg] = kv;
#pragma unroll
      for (int ii = 0; ii < 8; ++ii) vt[(dg + ii) * 72 + l] = vv[ii];
    }
    // S = Q K^T (64x64, K=32)
    f16x8 aq[4], bk[4];
#pragma unroll
    for (int i = 0; i < 4; ++i) aq[i] = *(const f16x8*)&qs[(i * 16 + ln) * 40 + q8];
#pragma unroll
    for (int j = 0; j < 4; ++j) bk[j] = *(const f16x8*)&ks[(j * 16 + ln) * 40 + q8];
    f32x4 sc[4][4] = {};
#pragma unroll
    for (int i = 0; i < 4; ++i)
#pragma unroll
      for (int j = 0; j < 4; ++j) sc[i][j] = mfma_16x16x32(aq[i], bk[j], sc[i][j]);

    // softmax rows; deferred normalization
    float rs[4][4];
#pragma unroll
    for (int i = 0; i < 4; ++i)
#pragma unroll
      for (int r = 0; r < 4; ++r) {
        float m = -1e30f;
#pragma unroll
        for (int j = 0; j < 4; ++j) m = fmaxf(m, sc[i][j][r]);
#pragma unroll
        for (int off = 1; off < 16; off <<= 1) m = fmaxf(m, __shfl_xor(m, off, 64));
        float sum = 0.f;
#pragma unroll
        for (int j = 0; j < 4; ++j) {
          float p = __expf(sc[i][j][r] - m);
          sc[i][j][r] = p;
          sum += p;
        }
#pragma unroll
        for (int off = 1; off < 16; off <<= 1) sum += __shfl_xor(sum, off, 64);
        rs[i][r] = 1.0f / sum;
      }

    // P -> ps (overlays qs/ks; same-wave in-order DS after aq/bk reads)
#pragma unroll
    for (int i = 0; i < 4; ++i)
#pragma unroll
      for (int j = 0; j < 4; ++j)
#pragma unroll
        for (int r = 0; r < 4; ++r)
          ps[(i * 16 + quad * 4 + r) * 72 + j * 16 + ln] = (f16)sc[i][j][r];

    // O = P V (64x32, K=64)
    f32x4 oc[4][2] = {};
#pragma unroll
    for (int k2 = 0; k2 < 2; ++k2) {
      f16x8 ap[4], bv[2];
#pragma unroll
      for (int i = 0; i < 4; ++i)
        ap[i] = *(const f16x8*)&ps[(i * 16 + ln) * 72 + k2 * 32 + q8];
#pragma unroll
      for (int j = 0; j < 2; ++j)
        bv[j] = *(const f16x8*)&vt[(j * 16 + ln) * 72 + k2 * 32 + q8];
#pragma unroll
      for (int i = 0; i < 4; ++i)
#pragma unroll
        for (int j = 0; j < 2; ++j) oc[i][j] = mfma_16x16x32(ap[i], bv[j], oc[i][j]);
    }

    // normalize -> obuf (overlays ps; reads done) -> vectorized store
#pragma unroll
    for (int i = 0; i < 4; ++i)
#pragma unroll
      for (int j = 0; j < 2; ++j)
#pragma unroll
        for (int r = 0; r < 4; ++r)
          obuf[(i * 16 + quad * 4 + r) * 40 + j * 16 + ln] =
              (f16)(oc[i][j][r] * rs[i][r]);
    {
      int row = lane >> 1, hf = lane & 1;
#pragma unroll
      for (int rr = 0; rr < 2; ++rr) {
        int rw = rr * 32 + row;
        const f16* ob = &obuf[rw * 40 + hf * 16];
        f16x8 o0 = *(const f16x8*)ob;
        f16x8 o1 = *(const f16x8*)(ob + 8);
        f16* gp = attnout + (sbase + rw) * 384 + hh * 32 + hf * 16;
        *(f16x8*)gp = o0;
        *(f16x8*)(gp + 8) = o1;
      }
    }
  }
}

// ---------------- proj GEMM: out = (attn + lepe) @ pw^T + bias (fp32) ----------------
// XCD-chunked grid (A re-read 3x hits L2); epilogue as R4.
__global__ __launch_bounds__(256) void k_proj(const f16* __restrict__ A1,
                                              const f16* __restrict__ A2,
                                              const f16* __restrict__ Bt,
                                              const float* __restrict__ bias,
                                              float* __restrict__ Cf) {
  __shared__ alignas(16) f16 As[128 * 64];
  __shared__ alignas(16) f16 Bs[128 * 64];
  const int tid = threadIdx.x;
  const int lane = tid & 63;
  const int wave = tid >> 6;
  const int wr = wave >> 1, wc = wave & 1;
  const int ln = lane & 15, quad = lane >> 4, q8 = quad * 8;
  const int bid = blockIdx.x;
  const int xcd = bid & 7;
  const int s = bid >> 3;        // 0..191
  const int mq = s / 3;          // 0..63
  const int mt = xcd * 64 + mq;  // 0..511
  const int nt = s - mq * 3;     // 0..2
  const long m0 = (long)mt * 128;
  const int n0 = nt * 128;

  f32x4 acc[4][4] = {};
  for (int k0 = 0; k0 < 384; k0 += 64) {
#pragma unroll
    for (int r = 0; r < 4; ++r) {
      int flat = r * 256 + tid;
      int row = flat >> 3, c8 = flat & 7;
      int sc8 = (c8 ^ (row & 7)) * 8;
      long ai = (m0 + row) * 384 + k0 + sc8;
      f16x8 s2 = *(const f16x8*)&A1[ai] + *(const f16x8*)&A2[ai];
      *(f16x8*)&As[flat * 8] = s2;
      gl_lds16(&Bt[(long)(n0 + row) * 384 + k0 + sc8], &Bs[flat * 8]);
    }
    __syncthreads();
#pragma unroll
    for (int ks = 0; ks < 2; ++ks) {
      f16x8 a[4], b[4];
#pragma unroll
      for (int i = 0; i < 4; ++i)
        a[i] = *(const f16x8*)&As[(wr * 64 + i * 16 + ln) * 64 +
                                  ((ks * 4 + quad) ^ (ln & 7)) * 8];
#pragma unroll
      for (int j = 0; j < 4; ++j)
        b[j] = *(const f16x8*)&Bs[(wc * 64 + j * 16 + ln) * 64 +
                                  ((ks * 4 + quad) ^ (ln & 7)) * 8];
#pragma unroll
      for (int i = 0; i < 4; ++i)
#pragma unroll
        for (int j = 0; j < 4; ++j)
          acc[i][j] = mfma_16x16x32(a[i], b[j], acc[i][j]);
    }
    __syncthreads();
  }

#pragma unroll
  for (int i = 0; i < 4; ++i)
#pragma unroll
    for (int j = 0; j < 4; ++j) {
      int gc = n0 + wc * 64 + j * 16 + ln;
#pragma unroll
      for (int r = 0; r < 4; ++r) {
        long gr = m0 + wr * 64 + i * 16 + quad * 4 + r;
        Cf[gr * 384 + gc] = acc[i][j][r] + bias[gc];
      }
    }
}

// ---------------- launch ----------------
extern "C" void kernel_launch(void* const* d_in, const int* in_sizes, int n_in,
                              void* d_out, int out_size, void* d_ws, size_t ws_size,
                              hipStream_t stream) {
  const float* x = (const float*)d_in[0];
  const float* qkv_w = (const float*)d_in[1];
  const float* proj_w = (const float*)d_in[2];
  const float* proj_b = (const float*)d_in[3];
  const float* lepe_w = (const float*)d_in[4];
  const float* lepe_b = (const float*)d_in[5];
  float* out = (float*)d_out;

  char* ws = (char*)d_ws;
  f16* w16 = (f16*)(ws + 0);              //     884,736 B
  f16* pw16 = (f16*)(ws + 884736);        //     294,912 B
  f16* x16 = (f16*)(ws + 1179648);        //  50,331,648 B (dead after k_qkv)
  f16* attnout = x16;                     //  reuses x16 region
  f16* lepe16 = (f16*)(ws + 51511296);    //  50,331,648 B
  f16* qkv16 = (f16*)(ws + 101842944);    // 150,994,944 B  (total 252,837,888 B)

  k_cvt<<<216, 256, 0, stream>>>(qkv_w, w16, 55296);
  k_cvt<<<72, 256, 0, stream>>>(proj_w, pw16, 18432);
  k_prep<<<12288, 256, 0, stream>>>(x, lepe_w, lepe_b, x16, lepe16);
  k_qkv<<<512 * 9, 256, 0, stream>>>(x16, w16, qkv16);
  k_attn<<<1024, 256, 0, stream>>>(qkv16, attnout);
  k_proj<<<512 * 3, 256, 0, stream>>>(attnout, lepe16, pw16, proj_b, out);
}

// Round 4
// 459.879 us; speedup vs baseline: 1.0251x; 1.0023x over previous
//
#include <hip/hip_runtime.h>

// LePEAttention: B=16, H=W=64, C=384, HEADS=12, hd=32, IDX=0 (vertical strips).
// Pipeline: k_prep (cvt x->x16 + lepe) -> k_qkv (MFMA GEMM, strip-permuted store)
//           -> k_attn (block=strip, 4 waves x 3 heads) -> k_proj (+lepe +bias, fp32).
// MFMA layouts (HW-verified): A[m=lane&15][k=quad*8+j]; B mirrored;
//   C/D: col=lane&15, row=quad*4+reg.
// R8 = R7 (XCD-chunked grid, measured: FETCH 224->30 MB) + vectorized epilogues:
//   k_qkv/k_proj accumulators go through an LDS transpose then f16x8/float4
//   stores (8/16 vector stores per thread vs 64 scalar). Attacks the measured
//   VALUBusy 30% > MfmaUtil 21% + 1.26 TB/s write inefficiency (32B segments).

typedef _Float16 f16;
typedef _Float16 f16x8 __attribute__((ext_vector_type(8)));
typedef float    f32x4 __attribute__((ext_vector_type(4)));

__device__ __forceinline__ f32x4 mfma_16x16x32(f16x8 a, f16x8 b, f32x4 c) {
  return __builtin_amdgcn_mfma_f32_16x16x32_f16(a, b, c, 0, 0, 0);
}

// async global->LDS 16B copy (dest must be wave-uniform base + lane*16)
__device__ __forceinline__ void gl_lds16(const f16* g, f16* l) {
  __builtin_amdgcn_global_load_lds((const __attribute__((address_space(1))) void*)g,
                                   (__attribute__((address_space(3))) void*)l, 16, 0, 0);
}

// ---------------- fp32 -> fp16 convert (weights) ----------------
__global__ __launch_bounds__(256) void k_cvt(const float* __restrict__ src,
                                             f16* __restrict__ dst, int n8) {
  int i = blockIdx.x * 256 + threadIdx.x;
  if (i >= n8) return;
  const f32x4* s4 = (const f32x4*)src;
  f32x4 a = s4[2 * i], b = s4[2 * i + 1];
  f16x8 o;
#pragma unroll
  for (int j = 0; j < 4; ++j) { o[j] = (f16)a[j]; o[4 + j] = (f16)b[j]; }
  *(f16x8*)&dst[(long)i * 8] = o;
}

// ---------------- fused cvt(x) + LePE conv ----------------
__global__ __launch_bounds__(256) void k_prep(const float* __restrict__ x,
                                              const float* __restrict__ lw,
                                              const float* __restrict__ lb,
                                              f16* __restrict__ x16,
                                              f16* __restrict__ lepe16) {
  __shared__ float ws[9 * 384];
  __shared__ float bs[384];
  for (int i = threadIdx.x; i < 3456; i += 256) {
    int c = i / 9, tap = i - c * 9;
    ws[tap * 384 + (c & 7) * 48 + (c >> 3)] = lw[i];
  }
  for (int i = threadIdx.x; i < 384; i += 256)
    bs[(i & 7) * 48 + (i >> 3)] = lb[i];
  __syncthreads();

  int chunk = blockIdx.x * 256 + threadIdx.x;
  int token = chunk / 48;
  int c0 = (chunk - token * 48) * 8;
  int cg = c0 >> 3;  // 0..47, stride-1 across lanes
  int b = token >> 12, n = token & 4095, h = n >> 6, w = n & 63;
  const float* xb = x + (long)(b << 12) * 384;

  float a8[8];
#pragma unroll
  for (int cc = 0; cc < 8; ++cc) a8[cc] = bs[cc * 48 + cg];
  f16x8 cv;
#pragma unroll
  for (int ky = 0; ky < 3; ++ky) {
    int hh = h + ky - 1;
    if (hh < 0 || hh > 63) continue;
#pragma unroll
    for (int kx = 0; kx < 3; ++kx) {
      int ww = w + kx - 1;
      if (ww < 0 || ww > 63) continue;
      const float* p = xb + (long)((hh << 6) + ww) * 384 + c0;
      float4 u = *(const float4*)p;
      float4 v = *(const float4*)(p + 4);
      float xs[8] = {u.x, u.y, u.z, u.w, v.x, v.y, v.z, v.w};
      if (ky == 1 && kx == 1) {
#pragma unroll
        for (int cc = 0; cc < 8; ++cc) cv[cc] = (f16)xs[cc];
      }
      int tap = ky * 3 + kx;
#pragma unroll
      for (int cc = 0; cc < 8; ++cc)
        a8[cc] += xs[cc] * ws[tap * 384 + cc * 48 + cg];
    }
  }
  f16x8 o;
#pragma unroll
  for (int cc = 0; cc < 8; ++cc) o[cc] = (f16)a8[cc];
  *(f16x8*)&x16[(long)token * 384 + c0] = cv;
  *(f16x8*)&lepe16[(long)token * 384 + c0] = o;
}

// ---------------- QKV GEMM: qkv[perm(t)][1152] = x16 @ w16^T ----------------
// 128x128 tile, BK=64, global_load_lds staging w/ 16B xor swizzle.
// Grid: XCD-chunked, nt fastest within each xcd's contiguous mt range -> each
// A-tile's 9 nt-passes hit the same XCD L2 (FETCH 224->30 MB, measured R7).
// Epilogue: acc -> LDS (two 64-row passes over staging buffers) -> f16x8 stores.
__global__ __launch_bounds__(256) void k_qkv(const f16* __restrict__ A,
                                             const f16* __restrict__ Bt,
                                             f16* __restrict__ C) {
  __shared__ alignas(16) f16 smem[2 * 128 * 64];
  f16* As = smem;
  f16* Bs = smem + 128 * 64;
  f16* buf = smem;  // epilogue overlay: 64 x 136 halfs = 17408 B <= 32768
  const int tid = threadIdx.x;
  const int lane = tid & 63;
  const int wave = tid >> 6;
  const int wr = wave >> 1, wc = wave & 1;
  const int ln = lane & 15, quad = lane >> 4;
  const int bid = blockIdx.x;
  const int xcd = bid & 7;
  const int s = bid >> 3;        // 0..575
  const int mq = s / 9;          // 0..63
  const int mt = xcd * 64 + mq;  // 0..511
  const int nt = s - mq * 9;     // 0..8
  const long m0 = (long)mt * 128;
  const int n0 = nt * 128;

  f32x4 acc[4][4] = {};
  for (int k0 = 0; k0 < 384; k0 += 64) {
#pragma unroll
    for (int r = 0; r < 4; ++r) {
      int flat = r * 256 + tid;
      int row = flat >> 3, c8 = flat & 7;
      int sc8 = (c8 ^ (row & 7)) * 8;
      gl_lds16(&A[(m0 + row) * 384 + k0 + sc8], &As[flat * 8]);
      gl_lds16(&Bt[(long)(n0 + row) * 384 + k0 + sc8], &Bs[flat * 8]);
    }
    __syncthreads();
#pragma unroll
    for (int ks = 0; ks < 2; ++ks) {
      f16x8 a[4], b[4];
#pragma unroll
      for (int i = 0; i < 4; ++i)
        a[i] = *(const f16x8*)&As[(wr * 64 + i * 16 + ln) * 64 +
                                  ((ks * 4 + quad) ^ (ln & 7)) * 8];
#pragma unroll
      for (int j = 0; j < 4; ++j)
        b[j] = *(const f16x8*)&Bs[(wc * 64 + j * 16 + ln) * 64 +
                                  ((ks * 4 + quad) ^ (ln & 7)) * 8];
#pragma unroll
      for (int i = 0; i < 4; ++i)
#pragma unroll
        for (int j = 0; j < 4; ++j)
          acc[i][j] = mfma_16x16x32(a[i], b[j], acc[i][j]);
    }
    __syncthreads();
  }

  // epilogue: two 64-row passes; LDS transpose then vectorized permuted store
  for (int half = 0; half < 2; ++half) {
    __syncthreads();
    if (wr == half) {
#pragma unroll
      for (int i = 0; i < 4; ++i)
#pragma unroll
        for (int j = 0; j < 4; ++j)
#pragma unroll
          for (int r = 0; r < 4; ++r)
            buf[(i * 16 + quad * 4 + r) * 136 + wc * 64 + j * 16 + ln] =
                (f16)acc[i][j][r];
    }
    __syncthreads();
#pragma unroll
    for (int it = 0; it < 4; ++it) {
      int flat = it * 256 + tid;  // 0..1023
      int row = flat >> 4;        // 0..63 (local)
      int c8 = flat & 15;
      int t = (int)m0 + half * 64 + row;
      int nn = t & 4095;
      long prow = (long)(t & ~4095) + ((nn & 63) << 6) + (nn >> 6);
      *(f16x8*)&C[prow * 1152 + n0 + c8 * 8] =
          *(const f16x8*)&buf[row * 136 + c8 * 8];
    }
  }
}

// ---------------- attention: block = strip, 4 waves x 3 heads ----------------
// qkv rows are strip-contiguous. Pure store to attnout (lepe added in proj).
__global__ __launch_bounds__(256) void k_attn(const f16* __restrict__ qkv,
                                              f16* __restrict__ attnout) {
  // per-wave LDS (halfs): qs@0 (64x40), ks@2560 (64x40), vt@5120 (32x72).
  // ps (64x72=4608) overlays qs+ks; obuf (64x40) overlays ps. total 7424 h/wave.
  __shared__ alignas(16) f16 shp[4][7424];
  const int lane = threadIdx.x & 63;
  const int wave = threadIdx.x >> 6;
  const int ln = lane & 15, quad = lane >> 4, q8 = quad * 8;
  const int b = blockIdx.x >> 6, w = blockIdx.x & 63;
  const long sbase = (long)b * 4096 + (long)w * 64;  // first permuted row of strip

  f16* qs = shp[wave];
  f16* ks = shp[wave] + 2560;
  f16* vt = shp[wave] + 5120;
  f16* ps = shp[wave];
  f16* obuf = shp[wave];
  const float qscale = 0.17677669529663687f;  // 32^-0.5

  for (int hi = 0; hi < 3; ++hi) {
    const int hh = wave * 3 + hi;
    // load q,k,v (64 tokens x 32 halfs each); rows stride 2304 B, 64 B used
#pragma unroll
    for (int r = 0; r < 4; ++r) {
      int flat = r * 64 + lane;
      int l = flat >> 2, dg = (flat & 3) * 8;
      long ta = (sbase + l) * 1152 + hh * 32 + dg;
      f16x8 qv = *(const f16x8*)&qkv[ta];
      f16x8 kv = *(const f16x8*)&qkv[ta + 384];
      f16x8 vv = *(const f16x8*)&qkv[ta + 768];
      // pre-scale q by 1/sqrt(hd)
#pragma unroll
      for (int ii = 0; ii < 8; ++ii) qv[ii] = (f16)((float)qv[ii] * qscale);
      *(f16x8*)&qs[l * 40 + dg] = qv;
      *(f16x8*)&ks[l * 40 + dg] = kv;
#pragma unroll
      for (int ii = 0; ii < 8; ++ii) vt[(dg + ii) * 72 + l] = vv[ii];
    }
    // S = Q K^T (64x64, K=32)
    f16x8 aq[4], bk[4];
#pragma unroll
    for (int i = 0; i < 4; ++i) aq[i] = *(const f16x8*)&qs[(i * 16 + ln) * 40 + q8];
#pragma unroll
    for (int j = 0; j < 4; ++j) bk[j] = *(const f16x8*)&ks[(j * 16 + ln) * 40 + q8];
    f32x4 sc[4][4] = {};
#pragma unroll
    for (int i = 0; i < 4; ++i)
#pragma unroll
      for (int j = 0; j < 4; ++j) sc[i][j] = mfma_16x16x32(aq[i], bk[j], sc[i][j]);

    // softmax rows; deferred normalization
    float rs[4][4];
#pragma unroll
    for (int i = 0; i < 4; ++i)
#pragma unroll
      for (int r = 0; r < 4; ++r) {
        float m = -1e30f;
#pragma unroll
        for (int j = 0; j < 4; ++j) m = fmaxf(m, sc[i][j][r]);
#pragma unroll
        for (int off = 1; off < 16; off <<= 1) m = fmaxf(m, __shfl_xor(m, off, 64));
        float sum = 0.f;
#pragma unroll
        for (int j = 0; j < 4; ++j) {
          float p = __expf(sc[i][j][r] - m);
          sc[i][j][r] = p;
          sum += p;
        }
#pragma unroll
        for (int off = 1; off < 16; off <<= 1) sum += __shfl_xor(sum, off, 64);
        rs[i][r] = 1.0f / sum;
      }

    // P -> ps (overlays qs/ks; same-wave in-order DS after aq/bk reads)
#pragma unroll
    for (int i = 0; i < 4; ++i)
#pragma unroll
      for (int j = 0; j < 4; ++j)
#pragma unroll
        for (int r = 0; r < 4; ++r)
          ps[(i * 16 + quad * 4 + r) * 72 + j * 16 + ln] = (f16)sc[i][j][r];

    // O = P V (64x32, K=64)
    f32x4 oc[4][2] = {};
#pragma unroll
    for (int k2 = 0; k2 < 2; ++k2) {
      f16x8 ap[4], bv[2];
#pragma unroll
      for (int i = 0; i < 4; ++i)
        ap[i] = *(const f16x8*)&ps[(i * 16 + ln) * 72 + k2 * 32 + q8];
#pragma unroll
      for (int j = 0; j < 2; ++j)
        bv[j] = *(const f16x8*)&vt[(j * 16 + ln) * 72 + k2 * 32 + q8];
#pragma unroll
      for (int i = 0; i < 4; ++i)
#pragma unroll
        for (int j = 0; j < 2; ++j) oc[i][j] = mfma_16x16x32(ap[i], bv[j], oc[i][j]);
    }

    // normalize -> obuf (overlays ps; reads done) -> vectorized store
#pragma unroll
    for (int i = 0; i < 4; ++i)
#pragma unroll
      for (int j = 0; j < 2; ++j)
#pragma unroll
        for (int r = 0; r < 4; ++r)
          obuf[(i * 16 + quad * 4 + r) * 40 + j * 16 + ln] =
              (f16)(oc[i][j][r] * rs[i][r]);
    {
      int row = lane >> 1, hf = lane & 1;
#pragma unroll
      for (int rr = 0; rr < 2; ++rr) {
        int rw = rr * 32 + row;
        const f16* ob = &obuf[rw * 40 + hf * 16];
        f16x8 o0 = *(const f16x8*)ob;
        f16x8 o1 = *(const f16x8*)(ob + 8);
        f16* gp = attnout + (sbase + rw) * 384 + hh * 32 + hf * 16;
        *(f16x8*)gp = o0;
        *(f16x8*)(gp + 8) = o1;
      }
    }
  }
}

// ---------------- proj GEMM: out = (attn + lepe) @ pw^T + bias (fp32) ----------------
// XCD-chunked grid (A re-read 3x hits L2); LDS-transpose epilogue w/ float4 stores.
__global__ __launch_bounds__(256) void k_proj(const f16* __restrict__ A1,
                                              const f16* __restrict__ A2,
                                              const f16* __restrict__ Bt,
                                              const float* __restrict__ bias,
                                              float* __restrict__ Cf) {
  __shared__ alignas(16) f16 smem[2 * 128 * 64];
  f16* As = smem;
  f16* Bs = smem + 128 * 64;
  float* buff = (float*)smem;  // epilogue overlay: 32 x 132 fp32 = 16896 B <= 32768
  const int tid = threadIdx.x;
  const int lane = tid & 63;
  const int wave = tid >> 6;
  const int wr = wave >> 1, wc = wave & 1;
  const int ln = lane & 15, quad = lane >> 4;
  const int bid = blockIdx.x;
  const int xcd = bid & 7;
  const int s = bid >> 3;        // 0..191
  const int mq = s / 3;          // 0..63
  const int mt = xcd * 64 + mq;  // 0..511
  const int nt = s - mq * 3;     // 0..2
  const long m0 = (long)mt * 128;
  const int n0 = nt * 128;

  f32x4 acc[4][4] = {};
  for (int k0 = 0; k0 < 384; k0 += 64) {
#pragma unroll
    for (int r = 0; r < 4; ++r) {
      int flat = r * 256 + tid;
      int row = flat >> 3, c8 = flat & 7;
      int sc8 = (c8 ^ (row & 7)) * 8;
      long ai = (m0 + row) * 384 + k0 + sc8;
      f16x8 s2 = *(const f16x8*)&A1[ai] + *(const f16x8*)&A2[ai];
      *(f16x8*)&As[flat * 8] = s2;
      gl_lds16(&Bt[(long)(n0 + row) * 384 + k0 + sc8], &Bs[flat * 8]);
    }
    __syncthreads();
#pragma unroll
    for (int ks = 0; ks < 2; ++ks) {
      f16x8 a[4], b[4];
#pragma unroll
      for (int i = 0; i < 4; ++i)
        a[i] = *(const f16x8*)&As[(wr * 64 + i * 16 + ln) * 64 +
                                  ((ks * 4 + quad) ^ (ln & 7)) * 8];
#pragma unroll
      for (int j = 0; j < 4; ++j)
        b[j] = *(const f16x8*)&Bs[(wc * 64 + j * 16 + ln) * 64 +
                                  ((ks * 4 + quad) ^ (ln & 7)) * 8];
#pragma unroll
      for (int i = 0; i < 4; ++i)
#pragma unroll
        for (int j = 0; j < 4; ++j)
          acc[i][j] = mfma_16x16x32(a[i], b[j], acc[i][j]);
    }
    __syncthreads();
  }

  // epilogue: four 32-row passes; LDS transpose then float4 stores (+bias)
#pragma unroll
  for (int p = 0; p < 4; ++p) {
    __syncthreads();
    if (wr == (p >> 1)) {
      const int ib = (p & 1) * 2;
#pragma unroll
      for (int ii = 0; ii < 2; ++ii)
#pragma unroll
        for (int j = 0; j < 4; ++j)
#pragma unroll
          for (int r = 0; r < 4; ++r)
            buff[(ii * 16 + quad * 4 + r) * 132 + wc * 64 + j * 16 + ln] =
                acc[ib + ii][j][r];
    }
    __syncthreads();
#pragma unroll
    for (int it = 0; it < 4; ++it) {
      int flat = it * 256 + tid;  // 0..1023
      int row = flat >> 5;        // 0..31
      int c4 = flat & 31;         // 0..31
      long gr = m0 + p * 32 + row;
      int col = n0 + c4 * 4;
      float4 b4 = *(const float4*)&bias[col];
      float4 o = *(const float4*)&buff[row * 132 + c4 * 4];
      o.x += b4.x; o.y += b4.y; o.z += b4.z; o.w += b4.w;
      *(float4*)&Cf[gr * 384 + col] = o;
    }
  }
}

// ---------------- launch ----------------
extern "C" void kernel_launch(void* const* d_in, const int* in_sizes, int n_in,
                              void* d_out, int out_size, void* d_ws, size_t ws_size,
                              hipStream_t stream) {
  const float* x = (const float*)d_in[0];
  const float* qkv_w = (const float*)d_in[1];
  const float* proj_w = (const float*)d_in[2];
  const float* proj_b = (const float*)d_in[3];
  const float* lepe_w = (const float*)d_in[4];
  const float* lepe_b = (const float*)d_in[5];
  float* out = (float*)d_out;

  char* ws = (char*)d_ws;
  f16* w16 = (f16*)(ws + 0);              //     884,736 B
  f16* pw16 = (f16*)(ws + 884736);        //     294,912 B
  f16* x16 = (f16*)(ws + 1179648);        //  50,331,648 B (dead after k_qkv)
  f16* attnout = x16;                     //  reuses x16 region
  f16* lepe16 = (f16*)(ws + 51511296);    //  50,331,648 B
  f16* qkv16 = (f16*)(ws + 101842944);    // 150,994,944 B  (total 252,837,888 B)

  k_cvt<<<216, 256, 0, stream>>>(qkv_w, w16, 55296);
  k_cvt<<<72, 256, 0, stream>>>(proj_w, pw16, 18432);
  k_prep<<<12288, 256, 0, stream>>>(x, lepe_w, lepe_b, x16, lepe16);
  k_qkv<<<512 * 9, 256, 0, stream>>>(x16, w16, qkv16);
  k_attn<<<1024, 256, 0, stream>>>(qkv16, attnout);
  k_proj<<<512 * 3, 256, 0, stream>>>(attnout, lepe16, pw16, proj_b, out);
}

// Round 5
// 456.878 us; speedup vs baseline: 1.0319x; 1.0066x over previous
//
#include <hip/hip_runtime.h>

// LePEAttention: B=16, H=W=64, C=384, HEADS=12, hd=32, IDX=0 (vertical strips).
// Pipeline: k_prep (cvt x->x16 + lepe) -> k_qkv (MFMA GEMM, strip-permuted store)
//           -> k_attn (block=strip, 4 waves x 3 heads) -> k_proj (+lepe +bias, fp32).
// MFMA layouts (HW-verified): A[m=lane&15][k=quad*8+j]; B mirrored;
//   C/D: col=lane&15, row=quad*4+reg.
// R9: k_qkv rewritten as 256x128 tile, 512 threads, DOUBLE-BUFFERED 2-phase
//   pipeline (issue next-tile global_load_lds BEFORE computing current tile;
//   one barrier per K-step). R7/R8 proved k_qkv is latency/barrier-bound
//   (FETCH fix + store fix both matched counters, neutral time; no pipe >31%).
//   k_prep/k_attn/k_proj unchanged from R8 to isolate the variable.

typedef _Float16 f16;
typedef _Float16 f16x8 __attribute__((ext_vector_type(8)));
typedef float    f32x4 __attribute__((ext_vector_type(4)));

__device__ __forceinline__ f32x4 mfma_16x16x32(f16x8 a, f16x8 b, f32x4 c) {
  return __builtin_amdgcn_mfma_f32_16x16x32_f16(a, b, c, 0, 0, 0);
}

// async global->LDS 16B copy (dest must be wave-uniform base + lane*16)
__device__ __forceinline__ void gl_lds16(const f16* g, f16* l) {
  __builtin_amdgcn_global_load_lds((const __attribute__((address_space(1))) void*)g,
                                   (__attribute__((address_space(3))) void*)l, 16, 0, 0);
}

// ---------------- fp32 -> fp16 convert (weights) ----------------
__global__ __launch_bounds__(256) void k_cvt(const float* __restrict__ src,
                                             f16* __restrict__ dst, int n8) {
  int i = blockIdx.x * 256 + threadIdx.x;
  if (i >= n8) return;
  const f32x4* s4 = (const f32x4*)src;
  f32x4 a = s4[2 * i], b = s4[2 * i + 1];
  f16x8 o;
#pragma unroll
  for (int j = 0; j < 4; ++j) { o[j] = (f16)a[j]; o[4 + j] = (f16)b[j]; }
  *(f16x8*)&dst[(long)i * 8] = o;
}

// ---------------- fused cvt(x) + LePE conv ----------------
__global__ __launch_bounds__(256) void k_prep(const float* __restrict__ x,
                                              const float* __restrict__ lw,
                                              const float* __restrict__ lb,
                                              f16* __restrict__ x16,
                                              f16* __restrict__ lepe16) {
  __shared__ float ws[9 * 384];
  __shared__ float bs[384];
  for (int i = threadIdx.x; i < 3456; i += 256) {
    int c = i / 9, tap = i - c * 9;
    ws[tap * 384 + (c & 7) * 48 + (c >> 3)] = lw[i];
  }
  for (int i = threadIdx.x; i < 384; i += 256)
    bs[(i & 7) * 48 + (i >> 3)] = lb[i];
  __syncthreads();

  int chunk = blockIdx.x * 256 + threadIdx.x;
  int token = chunk / 48;
  int c0 = (chunk - token * 48) * 8;
  int cg = c0 >> 3;  // 0..47, stride-1 across lanes
  int b = token >> 12, n = token & 4095, h = n >> 6, w = n & 63;
  const float* xb = x + (long)(b << 12) * 384;

  float a8[8];
#pragma unroll
  for (int cc = 0; cc < 8; ++cc) a8[cc] = bs[cc * 48 + cg];
  f16x8 cv;
#pragma unroll
  for (int ky = 0; ky < 3; ++ky) {
    int hh = h + ky - 1;
    if (hh < 0 || hh > 63) continue;
#pragma unroll
    for (int kx = 0; kx < 3; ++kx) {
      int ww = w + kx - 1;
      if (ww < 0 || ww > 63) continue;
      const float* p = xb + (long)((hh << 6) + ww) * 384 + c0;
      float4 u = *(const float4*)p;
      float4 v = *(const float4*)(p + 4);
      float xs[8] = {u.x, u.y, u.z, u.w, v.x, v.y, v.z, v.w};
      if (ky == 1 && kx == 1) {
#pragma unroll
        for (int cc = 0; cc < 8; ++cc) cv[cc] = (f16)xs[cc];
      }
      int tap = ky * 3 + kx;
#pragma unroll
      for (int cc = 0; cc < 8; ++cc)
        a8[cc] += xs[cc] * ws[tap * 384 + cc * 48 + cg];
    }
  }
  f16x8 o;
#pragma unroll
  for (int cc = 0; cc < 8; ++cc) o[cc] = (f16)a8[cc];
  *(f16x8*)&x16[(long)token * 384 + c0] = cv;
  *(f16x8*)&lepe16[(long)token * 384 + c0] = o;
}

// ---------------- QKV GEMM: qkv[perm(t)][1152] = x16 @ w16^T ----------------
// 256x128 tile, BK=64, 512 threads (8 waves: wr=wv>>1 owns 64 m-rows, wc=wv&1
// owns 64 n-cols). Double-buffered LDS (96 KB, 1 block/CU), 2-phase pipeline:
//   prologue stage -> for t: {stage t+1 into other buffer; ds_read+MFMA on
//   current; one __syncthreads (drains vmcnt+lgkm)}.
// Loads for tile t+1 fly during tile t's compute -> latency hidden.
// Grid: XCD-chunked (2304 = 8 * 288), nt fastest -> A-panel L2-resident.
// Epilogue: 2 passes of 128 rows; LDS transpose -> f16x8 permuted stores.
__global__ __launch_bounds__(512) void k_qkv(const f16* __restrict__ A,
                                             const f16* __restrict__ Bt,
                                             f16* __restrict__ C) {
  // halfs: As0 @0 (16384), As1 @16384, Bs0 @32768 (8192), Bs1 @40960. 96 KB.
  __shared__ alignas(16) f16 smem[49152];
  f16* ebuf = smem;  // epilogue overlay: 128 x 136 halfs = 34816 B
  const int tid = threadIdx.x;
  const int lane = tid & 63;
  const int wave = tid >> 6;
  const int wr = wave >> 1, wc = wave & 1;
  const int ln = lane & 15, quad = lane >> 4;
  const int bid = blockIdx.x;
  const int xcd = bid & 7;
  const int s = bid >> 3;        // 0..287
  const int mq = s / 9;          // 0..31
  const int mt = xcd * 32 + mq;  // 0..255
  const int nt = s - mq * 9;     // 0..8
  const long m0 = (long)mt * 256;
  const int n0 = nt * 128;

  // stage one 64-wide K-slice of A(256 rows) and B(128 rows) into buffers
  auto stage = [&](int buf, int k0) {
    f16* Asb = smem + buf * 16384;
    f16* Bsb = smem + 32768 + buf * 8192;
#pragma unroll
    for (int r = 0; r < 4; ++r) {
      int flat = r * 512 + tid;          // 0..2047
      int row = flat >> 3, c8 = flat & 7;
      int sc8 = (c8 ^ (row & 7)) * 8;
      gl_lds16(&A[(m0 + row) * 384 + k0 + sc8], &Asb[flat * 8]);
    }
#pragma unroll
    for (int r = 0; r < 2; ++r) {
      int flat = r * 512 + tid;          // 0..1023
      int row = flat >> 3, c8 = flat & 7;
      int sc8 = (c8 ^ (row & 7)) * 8;
      gl_lds16(&Bt[(long)(n0 + row) * 384 + k0 + sc8], &Bsb[flat * 8]);
    }
  };

  f32x4 acc[4][4] = {};
  stage(0, 0);
  __syncthreads();  // compiler drains vmcnt(0) before barrier
  int cur = 0;
  for (int t = 0; t < 6; ++t) {
    if (t < 5) stage(cur ^ 1, (t + 1) * 64);  // prefetch flies during compute
    const f16* Ac = smem + cur * 16384;
    const f16* Bc = smem + 32768 + cur * 8192;
#pragma unroll
    for (int ks = 0; ks < 2; ++ks) {
      f16x8 a[4], b[4];
#pragma unroll
      for (int i = 0; i < 4; ++i)
        a[i] = *(const f16x8*)&Ac[(wr * 64 + i * 16 + ln) * 64 +
                                  ((ks * 4 + quad) ^ (ln & 7)) * 8];
#pragma unroll
      for (int j = 0; j < 4; ++j)
        b[j] = *(const f16x8*)&Bc[(wc * 64 + j * 16 + ln) * 64 +
                                  ((ks * 4 + quad) ^ (ln & 7)) * 8];
#pragma unroll
      for (int i = 0; i < 4; ++i)
#pragma unroll
        for (int j = 0; j < 4; ++j)
          acc[i][j] = mfma_16x16x32(a[i], b[j], acc[i][j]);
    }
    __syncthreads();  // drains prefetch (flew during compute) + ds reads
    cur ^= 1;
  }

  // epilogue: two 128-row passes; LDS transpose then vectorized permuted store
  for (int p = 0; p < 2; ++p) {
    if ((wr >> 1) == p) {
      const int lr0 = (wr & 1) * 64;
#pragma unroll
      for (int i = 0; i < 4; ++i)
#pragma unroll
        for (int j = 0; j < 4; ++j)
#pragma unroll
          for (int r = 0; r < 4; ++r)
            ebuf[(lr0 + i * 16 + quad * 4 + r) * 136 + wc * 64 + j * 16 + ln] =
                (f16)acc[i][j][r];
    }
    __syncthreads();
#pragma unroll
    for (int it = 0; it < 4; ++it) {
      int flat = it * 512 + tid;  // 0..2047
      int row = flat >> 4;        // 0..127 (local)
      int c8 = flat & 15;
      int t = (int)m0 + p * 128 + row;
      int nn = t & 4095;
      long prow = (long)(t & ~4095) + ((nn & 63) << 6) + (nn >> 6);
      *(f16x8*)&C[prow * 1152 + n0 + c8 * 8] =
          *(const f16x8*)&ebuf[row * 136 + c8 * 8];
    }
    __syncthreads();
  }
}

// ---------------- attention: block = strip, 4 waves x 3 heads ----------------
// qkv rows are strip-contiguous. Pure store to attnout (lepe added in proj).
__global__ __launch_bounds__(256) void k_attn(const f16* __restrict__ qkv,
                                              f16* __restrict__ attnout) {
  // per-wave LDS (halfs): qs@0 (64x40), ks@2560 (64x40), vt@5120 (32x72).
  // ps (64x72=4608) overlays qs+ks; obuf (64x40) overlays ps. total 7424 h/wave.
  __shared__ alignas(16) f16 shp[4][7424];
  const int lane = threadIdx.x & 63;
  const int wave = threadIdx.x >> 6;
  const int ln = lane & 15, quad = lane >> 4, q8 = quad * 8;
  const int b = blockIdx.x >> 6, w = blockIdx.x & 63;
  const long sbase = (long)b * 4096 + (long)w * 64;  // first permuted row of strip

  f16* qs = shp[wave];
  f16* ks = shp[wave] + 2560;
  f16* vt = shp[wave] + 5120;
  f16* ps = shp[wave];
  f16* obuf = shp[wave];
  const float qscale = 0.17677669529663687f;  // 32^-0.5

  for (int hi = 0; hi < 3; ++hi) {
    const int hh = wave * 3 + hi;
    // load q,k,v (64 tokens x 32 halfs each); rows stride 2304 B, 64 B used
#pragma unroll
    for (int r = 0; r < 4; ++r) {
      int flat = r * 64 + lane;
      int l = flat >> 2, dg = (flat & 3) * 8;
      long ta = (sbase + l) * 1152 + hh * 32 + dg;
      f16x8 qv = *(const f16x8*)&qkv[ta];
      f16x8 kv = *(const f16x8*)&qkv[ta + 384];
      f16x8 vv = *(const f16x8*)&qkv[ta + 768];
      // pre-scale q by 1/sqrt(hd)
#pragma unroll
      for (int ii = 0; ii < 8; ++ii) qv[ii] = (f16)((float)qv[ii] * qscale);
      *(f16x8*)&qs[l * 40 + dg] = qv;
      *(f16x8*)&ks[l * 40 + dg] = kv;
#pragma unroll
      for (int ii = 0; ii < 8; ++ii) vt[(dg + ii) * 72 + l] = vv[ii];
    }
    // S = Q K^T (64x64, K=32)
    f16x8 aq[4], bk[4];
#pragma unroll
    for (int i = 0; i < 4; ++i) aq[i] = *(const f16x8*)&qs[(i * 16 + ln) * 40 + q8];
#pragma unroll
    for (int j = 0; j < 4; ++j) bk[j] = *(const f16x8*)&ks[(j * 16 + ln) * 40 + q8];
    f32x4 sc[4][4] = {};
#pragma unroll
    for (int i = 0; i < 4; ++i)
#pragma unroll
      for (int j = 0; j < 4; ++j) sc[i][j] = mfma_16x16x32(aq[i], bk[j], sc[i][j]);

    // softmax rows; deferred normalization
    float rs[4][4];
#pragma unroll
    for (int i = 0; i < 4; ++i)
#pragma unroll
      for (int r = 0; r < 4; ++r) {
        float m = -1e30f;
#pragma unroll
        for (int j = 0; j < 4; ++j) m = fmaxf(m, sc[i][j][r]);
#pragma unroll
        for (int off = 1; off < 16; off <<= 1) m = fmaxf(m, __shfl_xor(m, off, 64));
        float sum = 0.f;
#pragma unroll
        for (int j = 0; j < 4; ++j) {
          float p = __expf(sc[i][j][r] - m);
          sc[i][j][r] = p;
          sum += p;
        }
#pragma unroll
        for (int off = 1; off < 16; off <<= 1) sum += __shfl_xor(sum, off, 64);
        rs[i][r] = 1.0f / sum;
      }

    // P -> ps (overlays qs/ks; same-wave in-order DS after aq/bk reads)
#pragma unroll
    for (int i = 0; i < 4; ++i)
#pragma unroll
      for (int j = 0; j < 4; ++j)
#pragma unroll
        for (int r = 0; r < 4; ++r)
          ps[(i * 16 + quad * 4 + r) * 72 + j * 16 + ln] = (f16)sc[i][j][r];

    // O = P V (64x32, K=64)
    f32x4 oc[4][2] = {};
#pragma unroll
    for (int k2 = 0; k2 < 2; ++k2) {
      f16x8 ap[4], bv[2];
#pragma unroll
      for (int i = 0; i < 4; ++i)
        ap[i] = *(const f16x8*)&ps[(i * 16 + ln) * 72 + k2 * 32 + q8];
#pragma unroll
      for (int j = 0; j < 2; ++j)
        bv[j] = *(const f16x8*)&vt[(j * 16 + ln) * 72 + k2 * 32 + q8];
#pragma unroll
      for (int i = 0; i < 4; ++i)
#pragma unroll
        for (int j = 0; j < 2; ++j) oc[i][j] = mfma_16x16x32(ap[i], bv[j], oc[i][j]);
    }

    // normalize -> obuf (overlays ps; reads done) -> vectorized store
#pragma unroll
    for (int i = 0; i < 4; ++i)
#pragma unroll
      for (int j = 0; j < 2; ++j)
#pragma unroll
        for (int r = 0; r < 4; ++r)
          obuf[(i * 16 + quad * 4 + r) * 40 + j * 16 + ln] =
              (f16)(oc[i][j][r] * rs[i][r]);
    {
      int row = lane >> 1, hf = lane & 1;
#pragma unroll
      for (int rr = 0; rr < 2; ++rr) {
        int rw = rr * 32 + row;
        const f16* ob = &obuf[rw * 40 + hf * 16];
        f16x8 o0 = *(const f16x8*)ob;
        f16x8 o1 = *(const f16x8*)(ob + 8);
        f16* gp = attnout + (sbase + rw) * 384 + hh * 32 + hf * 16;
        *(f16x8*)gp = o0;
        *(f16x8*)(gp + 8) = o1;
      }
    }
  }
}

// ---------------- proj GEMM: out = (attn + lepe) @ pw^T + bias (fp32) ----------------
// XCD-chunked grid (A re-read 3x hits L2); LDS-transpose epilogue w/ float4 stores.
__global__ __launch_bounds__(256) void k_proj(const f16* __restrict__ A1,
                                              const f16* __restrict__ A2,
                                              const f16* __restrict__ Bt,
                                              const float* __restrict__ bias,
                                              float* __restrict__ Cf) {
  __shared__ alignas(16) f16 smem[2 * 128 * 64];
  f16* As = smem;
  f16* Bs = smem + 128 * 64;
  float* buff = (float*)smem;  // epilogue overlay: 32 x 132 fp32 = 16896 B <= 32768
  const int tid = threadIdx.x;
  const int lane = tid & 63;
  const int wave = tid >> 6;
  const int wr = wave >> 1, wc = wave & 1;
  const int ln = lane & 15, quad = lane >> 4;
  const int bid = blockIdx.x;
  const int xcd = bid & 7;
  const int s = bid >> 3;        // 0..191
  const int mq = s / 3;          // 0..63
  const int mt = xcd * 64 + mq;  // 0..511
  const int nt = s - mq * 3;     // 0..2
  const long m0 = (long)mt * 128;
  const int n0 = nt * 128;

  f32x4 acc[4][4] = {};
  for (int k0 = 0; k0 < 384; k0 += 64) {
#pragma unroll
    for (int r = 0; r < 4; ++r) {
      int flat = r * 256 + tid;
      int row = flat >> 3, c8 = flat & 7;
      int sc8 = (c8 ^ (row & 7)) * 8;
      long ai = (m0 + row) * 384 + k0 + sc8;
      f16x8 s2 = *(const f16x8*)&A1[ai] + *(const f16x8*)&A2[ai];
      *(f16x8*)&As[flat * 8] = s2;
      gl_lds16(&Bt[(long)(n0 + row) * 384 + k0 + sc8], &Bs[flat * 8]);
    }
    __syncthreads();
#pragma unroll
    for (int ks = 0; ks < 2; ++ks) {
      f16x8 a[4], b[4];
#pragma unroll
      for (int i = 0; i < 4; ++i)
        a[i] = *(const f16x8*)&As[(wr * 64 + i * 16 + ln) * 64 +
                                  ((ks * 4 + quad) ^ (ln & 7)) * 8];
#pragma unroll
      for (int j = 0; j < 4; ++j)
        b[j] = *(const f16x8*)&Bs[(wc * 64 + j * 16 + ln) * 64 +
                                  ((ks * 4 + quad) ^ (ln & 7)) * 8];
#pragma unroll
      for (int i = 0; i < 4; ++i)
#pragma unroll
        for (int j = 0; j < 4; ++j)
          acc[i][j] = mfma_16x16x32(a[i], b[j], acc[i][j]);
    }
    __syncthreads();
  }

  // epilogue: four 32-row passes; LDS transpose then float4 stores (+bias)
#pragma unroll
  for (int p = 0; p < 4; ++p) {
    __syncthreads();
    if (wr == (p >> 1)) {
      const int ib = (p & 1) * 2;
#pragma unroll
      for (int ii = 0; ii < 2; ++ii)
#pragma unroll
        for (int j = 0; j < 4; ++j)
#pragma unroll
          for (int r = 0; r < 4; ++r)
            buff[(ii * 16 + quad * 4 + r) * 132 + wc * 64 + j * 16 + ln] =
                acc[ib + ii][j][r];
    }
    __syncthreads();
#pragma unroll
    for (int it = 0; it < 4; ++it) {
      int flat = it * 256 + tid;  // 0..1023
      int row = flat >> 5;        // 0..31
      int c4 = flat & 31;         // 0..31
      long gr = m0 + p * 32 + row;
      int col = n0 + c4 * 4;
      float4 b4 = *(const float4*)&bias[col];
      float4 o = *(const float4*)&buff[row * 132 + c4 * 4];
      o.x += b4.x; o.y += b4.y; o.z += b4.z; o.w += b4.w;
      *(float4*)&Cf[gr * 384 + col] = o;
    }
  }
}

// ---------------- launch ----------------
extern "C" void kernel_launch(void* const* d_in, const int* in_sizes, int n_in,
                              void* d_out, int out_size, void* d_ws, size_t ws_size,
                              hipStream_t stream) {
  const float* x = (const float*)d_in[0];
  const float* qkv_w = (const float*)d_in[1];
  const float* proj_w = (const float*)d_in[2];
  const float* proj_b = (const float*)d_in[3];
  const float* lepe_w = (const float*)d_in[4];
  const float* lepe_b = (const float*)d_in[5];
  float* out = (float*)d_out;

  char* ws = (char*)d_ws;
  f16* w16 = (f16*)(ws + 0);              //     884,736 B
  f16* pw16 = (f16*)(ws + 884736);        //     294,912 B
  f16* x16 = (f16*)(ws + 1179648);        //  50,331,648 B (dead after k_qkv)
  f16* attnout = x16;                     //  reuses x16 region
  f16* lepe16 = (f16*)(ws + 51511296);    //  50,331,648 B
  f16* qkv16 = (f16*)(ws + 101842944);    // 150,994,944 B  (total 252,837,888 B)

  k_cvt<<<216, 256, 0, stream>>>(qkv_w, w16, 55296);
  k_cvt<<<72, 256, 0, stream>>>(proj_w, pw16, 18432);
  k_prep<<<12288, 256, 0, stream>>>(x, lepe_w, lepe_b, x16, lepe16);
  k_qkv<<<2304, 512, 0, stream>>>(x16, w16, qkv16);
  k_attn<<<1024, 256, 0, stream>>>(qkv16, attnout);
  k_proj<<<512 * 3, 256, 0, stream>>>(attnout, lepe16, pw16, proj_b, out);
}